// Round 6
// baseline (456.096 us; speedup 1.0000x reference)
//
#include <hip/hip_runtime.h>
#include <hip/hip_bf16.h>
#include <cstdint>
#include <cstddef>

#define BB 2
#define NN 2048
#define DD 1024
#define HH 16
#define DKK 64
#define SCALE 0.125f
#define LOG2E 1.4426950408889634f

typedef __bf16 bf16;
typedef __bf16 bf16x4 __attribute__((ext_vector_type(4)));
typedef __bf16 bf16x8 __attribute__((ext_vector_type(8)));
typedef float f32x4 __attribute__((ext_vector_type(4)));
typedef short s16x4 __attribute__((ext_vector_type(4)));

// async global->LDS, 16B/lane; LDS dst = wave-uniform base + lane*16.
#define GLD(gp, lp)                                                            \
  __builtin_amdgcn_global_load_lds(                                            \
      (const __attribute__((address_space(1))) void*)(gp),                     \
      (__attribute__((address_space(3))) void*)(lp), 16, 0, 0)

// ---------------- fp32 -> bf16 convert, all 7 tensors in one dispatch ------
struct CvtArgs { const float* s[7]; bf16* d[7]; int n[7]; };

__global__ void k_cvt(CvtArgs a) {
  const int seg = blockIdx.y;
  const float* __restrict__ s = a.s[seg];
  bf16* __restrict__ d = a.d[seg];
  int i = (blockIdx.x * 256 + threadIdx.x) * 8;
  if (i >= a.n[seg]) return;
  float4 f0 = *(const float4*)(s + i);
  float4 f1 = *(const float4*)(s + i + 4);
  bf16x8 o;
  o[0] = (bf16)f0.x; o[1] = (bf16)f0.y; o[2] = (bf16)f0.z; o[3] = (bf16)f0.w;
  o[4] = (bf16)f1.x; o[5] = (bf16)f1.y; o[6] = (bf16)f1.z; o[7] = (bf16)f1.w;
  *(bf16x8*)(d + i) = o;
}

// ---------------- GEMM body: out = oscale*(A @ W^T + bias) -----------------
// A:[M][1024] bf16, W:[1024][1024] bf16 (B^T layout). BK=64, GLD staging,
// 2-barrier m97 structure. Tile 128 x BN.
// LDS chunk swizzle: 8 chunks(16B)/row, slot c holds global chunk c^(r&7).
// mode 0: bf16 [b][h][row][dk]; mode 2: bf16 [b][h][dk][row]; mode 3: fp32.
template <int BN>
__device__ __forceinline__ void gemm_body(
    const bf16* __restrict__ A, const bf16* __restrict__ W,
    const float* __restrict__ bias, bf16* __restrict__ outB,
    float* __restrict__ outF, int mode, float oscale, int m0, int n0) {
  const int K = 1024;
  constexpr int NI = BN / 32;        // B-frags per wave
  constexpr int BI = BN * 8 / 256;   // B staging insts (chunks/256)
  __shared__ bf16 lA[128 * 64];
  __shared__ bf16 lB[BN * 64];
  const int t = threadIdx.x;
  const int lane = t & 63, quad = lane >> 4, l16 = lane & 15, w = t >> 6;
  const int wm = (w >> 1) * 64, wn = (w & 1) * (BN / 2);

  f32x4 acc[4][NI] = {};

  // staging map: chunk i = i4*256+t -> row i>>3, global chunk (i&7)^(row&7)
  const bf16* gA[4]; const bf16* gB[BI];
#pragma unroll
  for (int i4 = 0; i4 < 4; i4++) {
    int i = i4 * 256 + t;
    int r = i >> 3, c = (i & 7) ^ (r & 7);
    gA[i4] = A + (size_t)(m0 + r) * K + c * 8;
  }
#pragma unroll
  for (int i4 = 0; i4 < BI; i4++) {
    int i = i4 * 256 + t;
    int r = i >> 3, c = (i & 7) ^ (r & 7);
    gB[i4] = W + (size_t)(n0 + r) * K + c * 8;
  }

  for (int kb = 0; kb < K; kb += 64) {
    __syncthreads();  // prev step's LDS reads done
#pragma unroll
    for (int i4 = 0; i4 < 4; i4++) GLD(gA[i4] + kb, lA + (i4 * 256 + t) * 8);
#pragma unroll
    for (int i4 = 0; i4 < BI; i4++) GLD(gB[i4] + kb, lB + (i4 * 256 + t) * 8);
    __syncthreads();  // staging complete

#pragma unroll
    for (int kb2 = 0; kb2 < 2; kb2++) {
      bf16x8 af[4], bfr[NI];
      const int ch = ((kb2 * 4 + quad) ^ (l16 & 7)) * 8;
#pragma unroll
      for (int i = 0; i < 4; i++)
        af[i] = *(const bf16x8*)(lA + (wm + i * 16 + l16) * 64 + ch);
#pragma unroll
      for (int i = 0; i < NI; i++)
        bfr[i] = *(const bf16x8*)(lB + (wn + i * 16 + l16) * 64 + ch);
#pragma unroll
      for (int mi = 0; mi < 4; mi++)
#pragma unroll
        for (int ni = 0; ni < NI; ni++)
          acc[mi][ni] = __builtin_amdgcn_mfma_f32_16x16x32_bf16(
              af[mi], bfr[ni], acc[mi][ni], 0, 0, 0);
    }
  }

  // epilogue: C/D layout col=lane&15, row=quad*4+reg
  if (mode == 2) {
    // Vt [b][h][dk][row] output: per-wave 64x64 LDS transpose, then
    // coalesced bf16x8 stores along `row` (verified round 1: +14us on qkv).
    __syncthreads();  // all waves done with lA/lB K-loop reads
    // wave scratch: [col][row] bf16, 16B-unit swizzle u ^= (col&7)
    bf16* scr = (w < 2 ? lA : lB) + (w & 1) * 4096;
#pragma unroll
    for (int ni = 0; ni < NI; ni++) {
      int c = ni * 16 + l16;                 // local col (dk)
      float bs = bias[n0 + wn + c];
#pragma unroll
      for (int mi = 0; mi < 4; mi++) {
        int u = (mi * 2 + (quad >> 1)) ^ (c & 7);  // 16B unit (rows rr>>3)
        bf16x4 pv;
#pragma unroll
        for (int r = 0; r < 4; r++)
          pv[r] = (bf16)((acc[mi][ni][r] + bs) * oscale);
        // rr = mi*16 + quad*4 + r; elem-in-unit = (rr&7) = (quad&1)*4 + r
        *(bf16x4*)(scr + c * 64 + u * 8 + (quad & 1) * 4) = pv;
      }
    }
    __syncthreads();
    {
      const int gm0 = m0 + wm;
      const int b = gm0 >> 11, row0 = gm0 & 2047;
#pragma unroll
      for (int it = 0; it < 8; it++) {
        int c = it * 8 + (lane >> 3);
        int u = (lane & 7) ^ (lane >> 3);
        bf16x8 val = *(const bf16x8*)(scr + c * 64 + u * 8);
        int gn = n0 + wn + c;
        int h = gn >> 6, dk = gn & 63;
        *(bf16x8*)(outB + ((size_t)(b * HH + h) * DKK + dk) * NN + row0 +
                   (lane & 7) * 8) = val;
      }
    }
    return;
  }
#pragma unroll
  for (int mi = 0; mi < 4; mi++) {
#pragma unroll
    for (int ni = 0; ni < NI; ni++) {
#pragma unroll
      for (int r = 0; r < 4; r++) {
        int gm = m0 + wm + mi * 16 + quad * 4 + r;
        int gn = n0 + wn + ni * 16 + l16;
        float v = (acc[mi][ni][r] + bias[gn]) * oscale;
        if (mode == 3) {
          outF[(size_t)gm * 1024 + gn] = v;
        } else {
          int b = gm >> 11, row = gm & 2047;
          int h = gn >> 6, dk = gn & 63;
          outB[((size_t)(b * HH + h) * NN + row) * DKK + dk] = (bf16)v;
        }
      }
    }
  }
}

struct QkvArgs {
  const bf16* A; const bf16* W; const float* b[3]; bf16* o[3]; float sc0;
};

// grid (x=m-panel 32, y=n-panel 8, z=gemm): XCD = linear_id%8 = m-panel%8,
// so all 24 blocks (8 n-panels x 3 gemms) sharing an A panel sit on ONE XCD
// -> A (24MB, the big tensor) fetched ~once; W panels cycle through L2/L3.
__global__ __launch_bounds__(256, 3) void k_qkv(QkvArgs g) {
  const int z = blockIdx.z;
  gemm_body<128>(g.A + (size_t)z * 4194304, g.W + (size_t)z * 1048576,
                 g.b[z], g.o[z], nullptr, z == 2 ? 2 : 0,
                 z == 0 ? g.sc0 : 1.0f, blockIdx.x * 128, blockIdx.y * 128);
}

// grid (x=m-panel 32, y=n-panel 16): XCD = m-panel%8 -> Ao (8MB) shared per
// XCD; W (2MB) cycles. 512 blocks, 24KB LDS.
__global__ __launch_bounds__(256, 4) void k_oproj(
    const bf16* __restrict__ A, const bf16* __restrict__ W,
    const float* __restrict__ bias, float* __restrict__ out) {
  gemm_body<64>(A, W, bias, nullptr, out, 3, 1.0f, blockIdx.x * 128,
                blockIdx.y * 64);
}

// ---------------- flash attention (key-split waves, no-max softmax) --------
// Qp pre-scaled by SCALE*LOG2E. Qp,Kp:[B][H][N][DK]; Vt:[B][H][DK][N];
// Ao:[B][N][H*DK].
// ROUND-0 VERIFIED STRUCTURE: 512 thr = 8 waves = 4 qrow-pairs (wq)
// x 2 key-halves (kh). Wave (wq,kh): q-rows [qt*128+wq*32,+32) x keys
// [kh*64,+64) per 128-key tile. shfl row-sum (ones-MFMA regressed round 2);
// no s_setprio (regressed round 1). SoA kh-merge (round 5: -1.4M conflicts).
// Round-6 change: V is NOT LDS-staged. Per XCD only 4 bh's K+V = 2MB live
// (L2 4MB), and 16 qt-blocks share each bh's V -> V^T fragments are read
// directly from global (L2-hit), same index algebra as the old LDS path:
// dk = ni*16+l16, key = kt + kh*64 + tt*16 + quad*4 + r. Drops LDS 64->35KB
// (2 -> 4 blocks/CU; launch_bounds(512,8) pins VGPR<=64 so LDS is the cap),
// halves GLD staging, removes the V ds_read traffic + its bank conflicts.
__global__ __launch_bounds__(512, 8) void k_attn(
    const bf16* __restrict__ Qp, const bf16* __restrict__ Kp,
    const bf16* __restrict__ Vt, bf16* __restrict__ Ao) {
  __shared__ bf16 lK[2][128 * 64];  // 2 x 16KB (K dbuf; merge redO scratch)
  __shared__ float redL2[512];      // 2KB (kh=1 lj spill for merge)
  const int t = threadIdx.x;
  const int lane = t & 63, quad = lane >> 4, l16 = lane & 15, w = t >> 6;
  const int wq = w & 3;   // qrow pair
  const int kh = w >> 2;  // key half
  const int bh = blockIdx.x;  // XCD = bh%8 -> K/V L2-resident per XCD
  const int qt = blockIdx.y;
  const bf16* Qb = Qp + (size_t)bh * NN * DKK;
  const bf16* Kb = Kp + (size_t)bh * NN * DKK;
  const bf16* Vb = Vt + (size_t)bh * DKK * NN;

  // Q B-frags (n=qrow=l16, k=dk=quad*8+j); 2 strips of 16 rows
  const int qr0 = qt * 128 + wq * 32;
  bf16x8 qf[2][2];
#pragma unroll
  for (int j = 0; j < 2; j++)
#pragma unroll
    for (int kq = 0; kq < 2; kq++)
      qf[j][kq] = *(const bf16x8*)(Qb + (size_t)(qr0 + j * 16 + l16) * DKK +
                                   kq * 32 + quad * 8);

  float lj[2] = {0.f, 0.f};
  f32x4 oaccT[2][4] = {};  // O^T partials: rows dk=ni*16+quad*4+r, col=l16

  // K staging: lK chunk i: row i>>3, gchunk (i&7)^(r&7)
  const bf16* gK[2];
#pragma unroll
  for (int i2 = 0; i2 < 2; i2++) {
    int i = i2 * 512 + t;
    int rK = i >> 3, cK = (i & 7) ^ (rK & 7);
    gK[i2] = Kb + (size_t)rK * DKK + cK * 8;
  }
  const int swzK0 = (quad ^ (l16 & 7)) * 8;
  const int swzK1 = ((4 + quad) ^ (l16 & 7)) * 8;

  // V^T direct-global bases: row dk = ni*16+l16, key base kh*64 + quad*4
  const bf16* pV[4];
#pragma unroll
  for (int ni = 0; ni < 4; ni++)
    pV[ni] = Vb + (size_t)(ni * 16 + l16) * NN + kh * 64 + quad * 4;

  // prologue: stage K tile 0 into buffer 0
#pragma unroll
  for (int i2 = 0; i2 < 2; i2++) GLD(gK[i2], &lK[0][(i2 * 512 + t) * 8]);

  int p = 0;
  for (int kt = 0; kt < NN; kt += 128) {
    __syncthreads();  // tile-kt K GLDs drained; all waves done with buf p^1
    if (kt + 128 < NN) {
#pragma unroll
      for (int i2 = 0; i2 < 2; i2++)
        GLD(gK[i2] + (size_t)(kt + 128) * DKK, &lK[p ^ 1][(i2 * 512 + t) * 8]);
    }

    // S^T = K Q^T over this wave's key half (keys kh*64 + tt*16 + quad*4+r)
    f32x4 s[2][4];
#pragma unroll
    for (int tt = 0; tt < 4; tt++) {
      const bf16* kbase = &lK[p][((kh * 4 + tt) * 16 + l16) * 64];
      bf16x8 kf0 = *(const bf16x8*)(kbase + swzK0);
      bf16x8 kf1 = *(const bf16x8*)(kbase + swzK1);
#pragma unroll
      for (int j = 0; j < 2; j++) {
        f32x4 z = {0.f, 0.f, 0.f, 0.f};
        z = __builtin_amdgcn_mfma_f32_16x16x32_bf16(kf0, qf[j][0], z, 0, 0, 0);
        z = __builtin_amdgcn_mfma_f32_16x16x32_bf16(kf1, qf[j][1], z, 0, 0, 0);
        s[j][tt] = z;
      }
    }

    // P = exp2(S) straight (S already in log2 units); per-lane partial l
    s16x4 pa[2][4];
#pragma unroll
    for (int j = 0; j < 2; j++) {
      float rs = 0.f;
#pragma unroll
      for (int tt = 0; tt < 4; tt++) {
        bf16x4 pb;
#pragma unroll
        for (int r = 0; r < 4; r++) {
          float pe = __builtin_amdgcn_exp2f(s[j][tt][r]);
          rs += pe;
          pb[r] = (bf16)pe;
        }
        pa[j][tt] = __builtin_bit_cast(s16x4, pb);
      }
      lj[j] += rs;
    }

    // O^T += V^T P^T; V^T fragments straight from global (L2-resident)
#pragma unroll
    for (int ni = 0; ni < 4; ni++) {
      s16x4 vb[4];
#pragma unroll
      for (int tt = 0; tt < 4; tt++)
        vb[tt] = __builtin_bit_cast(
            s16x4, *(const bf16x4*)(pV[ni] + kt + tt * 16));
#pragma unroll
      for (int tt = 0; tt < 4; tt++)
#pragma unroll
        for (int j = 0; j < 2; j++)
          oaccT[j][ni] = __builtin_amdgcn_mfma_f32_16x16x16bf16_1k(
              vb[tt], pa[j][tt], oaccT[j][ni], 0, 0, 0);
    }
    p ^= 1;
  }

  // ---- cross key-half reduction (once per kernel) via LDS ----
  // SoA layout: vector slot c = j*4+ni at word (c*1024 + R*4), R = wq*64+lane.
  // Lanes stride 4 words -> 8-way b128 floor. 8 slots x 256 x 16B = 32KB = lK.
  __syncthreads();  // K-loop LDS use done; lK now scratch
  float* redO = (float*)&lK[0][0];
  const int R = wq * 64 + lane;
  if (kh == 1) {
#pragma unroll
    for (int j = 0; j < 2; j++)
#pragma unroll
      for (int ni = 0; ni < 4; ni++)
        *(f32x4*)(redO + ((j * 4 + ni) * 1024 + R * 4)) = oaccT[j][ni];
    redL2[R * 2 + 0] = lj[0];
    redL2[R * 2 + 1] = lj[1];
  }
  __syncthreads();
  if (kh == 0) {
#pragma unroll
    for (int j = 0; j < 2; j++)
#pragma unroll
      for (int ni = 0; ni < 4; ni++)
        oaccT[j][ni] += *(const f32x4*)(redO + ((j * 4 + ni) * 1024 + R * 4));
    lj[0] += redL2[R * 2 + 0];
    lj[1] += redL2[R * 2 + 1];

    const int b = bh >> 4, h = bh & 15;
#pragma unroll
    for (int j = 0; j < 2; j++) {
      float l = lj[j];
      l += __shfl_xor(l, 16);
      l += __shfl_xor(l, 32);
      const float inv = 1.0f / l;
      bf16* dst = Ao + ((size_t)(b * NN) + qr0 + j * 16 + l16) * DD +
                  h * DKK + quad * 4;
#pragma unroll
      for (int ni = 0; ni < 4; ni++) {
        bf16x4 ov;
#pragma unroll
        for (int r = 0; r < 4; r++) ov[r] = (bf16)(oaccT[j][ni][r] * inv);
        *(bf16x4*)(dst + ni * 16) = ov;
      }
    }
  }
}

extern "C" void kernel_launch(void* const* d_in, const int* in_sizes, int n_in,
                              void* d_out, int out_size, void* d_ws,
                              size_t ws_size, hipStream_t stream) {
  const float* qin = (const float*)d_in[0];
  const float* kin = (const float*)d_in[1];
  const float* vin = (const float*)d_in[2];
  const float* Wq = (const float*)d_in[3];
  const float* bq = (const float*)d_in[4];
  const float* Wk = (const float*)d_in[5];
  const float* bk = (const float*)d_in[6];
  const float* Wv = (const float*)d_in[7];
  const float* bv = (const float*)d_in[8];
  const float* Wo = (const float*)d_in[9];
  const float* bo = (const float*)d_in[10];
  float* out = (float*)d_out;

  const int MN = BB * NN * DD;  // 4M elems
  const int WNel = DD * DD;     // 1M elems
  bf16* ws = (bf16*)d_ws;
  bf16* Xb = ws;                 // 12M elems (q,k,v bf16)
  bf16* Wb = Xb + 3 * MN;        // 4M elems (Wq,Wk,Wv,Wo bf16)
  bf16* Qp = Wb + 4 * WNel;      // 4M
  bf16* Kp = Qp + MN;            // 4M
  bf16* Vt = Kp + MN;            // 4M   -> 28M elems = 56MB
  bf16* Ao = Xb;                 // alias: Xb dead after k_qkv

  CvtArgs ca{{qin, kin, vin, Wq, Wk, Wv, Wo},
             {Xb, Xb + MN, Xb + 2 * MN, Wb, Wb + WNel, Wb + 2 * WNel,
              Wb + 3 * WNel},
             {MN, MN, MN, WNel, WNel, WNel, WNel}};
  k_cvt<<<dim3(2048, 7), 256, 0, stream>>>(ca);

  QkvArgs g{Xb, Wb, {bq, bk, bv}, {Qp, Kp, Vt}, SCALE * LOG2E};
  k_qkv<<<dim3(32, 8, 3), 256, 0, stream>>>(g);
  k_attn<<<dim3(32, 16), 512, 0, stream>>>(Qp, Kp, Vt, Ao);
  k_oproj<<<dim3(32, 16), 256, 0, stream>>>(Ao, Wb + 3 * WNel, bo, out);
}

// Round 7
// 392.220 us; speedup vs baseline: 1.1629x; 1.1629x over previous
//
#include <hip/hip_runtime.h>
#include <hip/hip_bf16.h>
#include <cstdint>
#include <cstddef>

#define BB 2
#define NN 2048
#define DD 1024
#define HH 16
#define DKK 64
#define SCALE 0.125f
#define LOG2E 1.4426950408889634f

typedef __bf16 bf16;
typedef __bf16 bf16x4 __attribute__((ext_vector_type(4)));
typedef __bf16 bf16x8 __attribute__((ext_vector_type(8)));
typedef float f32x4 __attribute__((ext_vector_type(4)));
typedef short s16x4 __attribute__((ext_vector_type(4)));

// async global->LDS, 16B/lane; LDS dst = wave-uniform base + lane*16.
#define GLD(gp, lp)                                                            \
  __builtin_amdgcn_global_load_lds(                                            \
      (const __attribute__((address_space(1))) void*)(gp),                     \
      (__attribute__((address_space(3))) void*)(lp), 16, 0, 0)

// ---------------- fp32 -> bf16 convert, all 7 tensors in one dispatch ------
struct CvtArgs { const float* s[7]; bf16* d[7]; int n[7]; };

__global__ void k_cvt(CvtArgs a) {
  const int seg = blockIdx.y;
  const float* __restrict__ s = a.s[seg];
  bf16* __restrict__ d = a.d[seg];
  int i = (blockIdx.x * 256 + threadIdx.x) * 8;
  if (i >= a.n[seg]) return;
  float4 f0 = *(const float4*)(s + i);
  float4 f1 = *(const float4*)(s + i + 4);
  bf16x8 o;
  o[0] = (bf16)f0.x; o[1] = (bf16)f0.y; o[2] = (bf16)f0.z; o[3] = (bf16)f0.w;
  o[4] = (bf16)f1.x; o[5] = (bf16)f1.y; o[6] = (bf16)f1.z; o[7] = (bf16)f1.w;
  *(bf16x8*)(d + i) = o;
}

// ---------------- GEMM body: out = oscale*(A @ W^T + bias) -----------------
// A:[M][1024] bf16, W:[1024][1024] bf16 (B^T layout). BK=64, GLD staging,
// 2-barrier m97 structure. Tile 128 x BN.
// LDS chunk swizzle: 8 chunks(16B)/row, slot c holds global chunk c^(r&7).
// mode 0: bf16 [b][h][row][dk]; mode 2: bf16 [b][h][dk][row]; mode 3: fp32.
template <int BN>
__device__ __forceinline__ void gemm_body(
    const bf16* __restrict__ A, const bf16* __restrict__ W,
    const float* __restrict__ bias, bf16* __restrict__ outB,
    float* __restrict__ outF, int mode, float oscale, int m0, int n0) {
  const int K = 1024;
  constexpr int NI = BN / 32;        // B-frags per wave
  constexpr int BI = BN * 8 / 256;   // B staging insts (chunks/256)
  __shared__ bf16 lA[128 * 64];
  __shared__ bf16 lB[BN * 64];
  const int t = threadIdx.x;
  const int lane = t & 63, quad = lane >> 4, l16 = lane & 15, w = t >> 6;
  const int wm = (w >> 1) * 64, wn = (w & 1) * (BN / 2);

  f32x4 acc[4][NI] = {};

  // staging map: chunk i = i4*256+t -> row i>>3, global chunk (i&7)^(row&7)
  const bf16* gA[4]; const bf16* gB[BI];
#pragma unroll
  for (int i4 = 0; i4 < 4; i4++) {
    int i = i4 * 256 + t;
    int r = i >> 3, c = (i & 7) ^ (r & 7);
    gA[i4] = A + (size_t)(m0 + r) * K + c * 8;
  }
#pragma unroll
  for (int i4 = 0; i4 < BI; i4++) {
    int i = i4 * 256 + t;
    int r = i >> 3, c = (i & 7) ^ (r & 7);
    gB[i4] = W + (size_t)(n0 + r) * K + c * 8;
  }

  for (int kb = 0; kb < K; kb += 64) {
    __syncthreads();  // prev step's LDS reads done
#pragma unroll
    for (int i4 = 0; i4 < 4; i4++) GLD(gA[i4] + kb, lA + (i4 * 256 + t) * 8);
#pragma unroll
    for (int i4 = 0; i4 < BI; i4++) GLD(gB[i4] + kb, lB + (i4 * 256 + t) * 8);
    __syncthreads();  // staging complete

#pragma unroll
    for (int kb2 = 0; kb2 < 2; kb2++) {
      bf16x8 af[4], bfr[NI];
      const int ch = ((kb2 * 4 + quad) ^ (l16 & 7)) * 8;
#pragma unroll
      for (int i = 0; i < 4; i++)
        af[i] = *(const bf16x8*)(lA + (wm + i * 16 + l16) * 64 + ch);
#pragma unroll
      for (int i = 0; i < NI; i++)
        bfr[i] = *(const bf16x8*)(lB + (wn + i * 16 + l16) * 64 + ch);
#pragma unroll
      for (int mi = 0; mi < 4; mi++)
#pragma unroll
        for (int ni = 0; ni < NI; ni++)
          acc[mi][ni] = __builtin_amdgcn_mfma_f32_16x16x32_bf16(
              af[mi], bfr[ni], acc[mi][ni], 0, 0, 0);
    }
  }

  // epilogue: C/D layout col=lane&15, row=quad*4+reg
  if (mode == 2) {
    // Vt [b][h][dk][row] output: per-wave 64x64 LDS transpose, then
    // coalesced bf16x8 stores along `row` (verified round 1: +14us on qkv).
    __syncthreads();  // all waves done with lA/lB K-loop reads
    // wave scratch: [col][row] bf16, 16B-unit swizzle u ^= (col&7)
    bf16* scr = (w < 2 ? lA : lB) + (w & 1) * 4096;
#pragma unroll
    for (int ni = 0; ni < NI; ni++) {
      int c = ni * 16 + l16;                 // local col (dk)
      float bs = bias[n0 + wn + c];
#pragma unroll
      for (int mi = 0; mi < 4; mi++) {
        int u = (mi * 2 + (quad >> 1)) ^ (c & 7);  // 16B unit (rows rr>>3)
        bf16x4 pv;
#pragma unroll
        for (int r = 0; r < 4; r++)
          pv[r] = (bf16)((acc[mi][ni][r] + bs) * oscale);
        // rr = mi*16 + quad*4 + r; elem-in-unit = (rr&7) = (quad&1)*4 + r
        *(bf16x4*)(scr + c * 64 + u * 8 + (quad & 1) * 4) = pv;
      }
    }
    __syncthreads();
    {
      const int gm0 = m0 + wm;
      const int b = gm0 >> 11, row0 = gm0 & 2047;
#pragma unroll
      for (int it = 0; it < 8; it++) {
        int c = it * 8 + (lane >> 3);
        int u = (lane & 7) ^ (lane >> 3);
        bf16x8 val = *(const bf16x8*)(scr + c * 64 + u * 8);
        int gn = n0 + wn + c;
        int h = gn >> 6, dk = gn & 63;
        *(bf16x8*)(outB + ((size_t)(b * HH + h) * DKK + dk) * NN + row0 +
                   (lane & 7) * 8) = val;
      }
    }
    return;
  }
#pragma unroll
  for (int mi = 0; mi < 4; mi++) {
#pragma unroll
    for (int ni = 0; ni < NI; ni++) {
#pragma unroll
      for (int r = 0; r < 4; r++) {
        int gm = m0 + wm + mi * 16 + quad * 4 + r;
        int gn = n0 + wn + ni * 16 + l16;
        float v = (acc[mi][ni][r] + bias[gn]) * oscale;
        if (mode == 3) {
          outF[(size_t)gm * 1024 + gn] = v;
        } else {
          int b = gm >> 11, row = gm & 2047;
          int h = gn >> 6, dk = gn & 63;
          outB[((size_t)(b * HH + h) * NN + row) * DKK + dk] = (bf16)v;
        }
      }
    }
  }
}

struct QkvArgs {
  const bf16* A; const bf16* W; const float* b[3]; bf16* o[3]; float sc0;
};

// grid (x=m-panel 32, y=n-panel 8, z=gemm): XCD = linear_id%8 = m-panel%8,
// so all 24 blocks (8 n-panels x 3 gemms) sharing an A panel sit on ONE XCD
// -> A (24MB, the big tensor) fetched ~once; W panels cycle through L2/L3.
__global__ __launch_bounds__(256, 3) void k_qkv(QkvArgs g) {
  const int z = blockIdx.z;
  gemm_body<128>(g.A + (size_t)z * 4194304, g.W + (size_t)z * 1048576,
                 g.b[z], g.o[z], nullptr, z == 2 ? 2 : 0,
                 z == 0 ? g.sc0 : 1.0f, blockIdx.x * 128, blockIdx.y * 128);
}

// grid (x=m-panel 32, y=n-panel 16): XCD = m-panel%8 -> Ao (8MB) shared per
// XCD; W (2MB) cycles. 512 blocks, 24KB LDS.
__global__ __launch_bounds__(256, 4) void k_oproj(
    const bf16* __restrict__ A, const bf16* __restrict__ W,
    const float* __restrict__ bias, float* __restrict__ out) {
  gemm_body<64>(A, W, bias, nullptr, out, 3, 1.0f, blockIdx.x * 128,
                blockIdx.y * 64);
}

// ---------------- flash attention (key-split waves, no-max softmax) --------
// Qp pre-scaled by SCALE*LOG2E. Qp,Kp:[B][H][N][DK]; Vt:[B][H][DK][N];
// Ao:[B][N][H*DK].
// 512 thr = 8 waves = 4 qrow-pairs (wq) x 2 key-halves (kh); QBLK=128.
// Round-7 change vs round-5 (51.8us verified): KVBLK 128->64. Per buffer:
// [0,4096) K tile 64keys x 64dk, [4096,8192) V tile 64dk x 64keys, both
// 8 chunks(16B)/row with slot c holding global chunk c^(row&7). LDS
// 64->34KB -> 4 blocks/CU (was 2): more independent barrier groups to
// cover the per-tile lockstep drain. V IS LDS-staged (round-6 direct-global
// V: FETCH 12->370MB, 305us — scattered 8B global reads are not L2-free).
// Wave (wq,kh): q-rows [qt*128+wq*32,+32), keys [kt+kh*32,+32).
// shfl row-sum (ones-MFMA regressed r2); no s_setprio (regressed r1);
// SoA kh-merge (r5). Round-3's version of this retile had the V staging
// map left at 16 chunks/row — fixed here (8 chunks/row, mirror of K).
__global__ __launch_bounds__(512, 8) void k_attn(
    const bf16* __restrict__ Qp, const bf16* __restrict__ Kp,
    const bf16* __restrict__ Vt, bf16* __restrict__ Ao) {
  __shared__ bf16 lKV[2][8192];  // 32KB: per buf K 8KB + V 8KB
  __shared__ float redL2[512];   // 2KB (kh=1 lj spill for merge)
  const int t = threadIdx.x;
  const int lane = t & 63, quad = lane >> 4, l16 = lane & 15, w = t >> 6;
  const int wq = w & 3;   // qrow pair
  const int kh = w >> 2;  // key half (32 keys)
  const int bh = blockIdx.x;  // XCD = bh%8 -> K/V L2-resident per XCD
  const int qt = blockIdx.y;
  const bf16* Qb = Qp + (size_t)bh * NN * DKK;
  const bf16* Kb = Kp + (size_t)bh * NN * DKK;
  const bf16* Vb = Vt + (size_t)bh * DKK * NN;

  // Q B-frags (n=qrow=l16, k=dk=quad*8+j); 2 strips of 16 rows
  const int qr0 = qt * 128 + wq * 32;
  bf16x8 qf[2][2];
#pragma unroll
  for (int j = 0; j < 2; j++)
#pragma unroll
    for (int kq = 0; kq < 2; kq++)
      qf[j][kq] = *(const bf16x8*)(Qb + (size_t)(qr0 + j * 16 + l16) * DKK +
                                   kq * 32 + quad * 8);

  float lj[2] = {0.f, 0.f};
  f32x4 oaccT[2][4] = {};  // O^T partials: rows dk=ni*16+quad*4+r, col=l16

  // staging: both K and V tiles are 64 rows x 8 chunks(16B); chunk i=t ->
  // row i>>3, slot i&7 holds global chunk (i&7)^(row&7). 512 thr x 16B = 8KB.
  const int rS = t >> 3, cS = (t & 7) ^ (rS & 7);
  const bf16* gK = Kb + (size_t)rS * DKK + cS * 8;  // K row = key
  const bf16* gV = Vb + (size_t)rS * NN + cS * 8;   // V row = dk, cols = keys
  const int swzK0 = (quad ^ (l16 & 7)) * 8;
  const int swzK1 = ((4 + quad) ^ (l16 & 7)) * 8;

  // prologue: stage tile 0 into buffer 0
  GLD(gK, &lKV[0][t * 8]);
  GLD(gV, &lKV[0][4096 + t * 8]);

  int p = 0;
  for (int kt = 0; kt < NN; kt += 64) {
    __syncthreads();  // tile-kt GLDs drained; all waves done with buf p^1
    if (kt + 64 < NN) {
      GLD(gK + (size_t)(kt + 64) * DKK, &lKV[p ^ 1][t * 8]);
      GLD(gV + (kt + 64), &lKV[p ^ 1][4096 + t * 8]);
    }

    // S^T = K Q^T over this wave's key half (keys kh*32 + tt*16 + quad*4+r)
    f32x4 s[2][2];
#pragma unroll
    for (int tt = 0; tt < 2; tt++) {
      const bf16* kbase = &lKV[p][((kh * 2 + tt) * 16 + l16) * 64];
      bf16x8 kf0 = *(const bf16x8*)(kbase + swzK0);
      bf16x8 kf1 = *(const bf16x8*)(kbase + swzK1);
#pragma unroll
      for (int j = 0; j < 2; j++) {
        f32x4 z = {0.f, 0.f, 0.f, 0.f};
        z = __builtin_amdgcn_mfma_f32_16x16x32_bf16(kf0, qf[j][0], z, 0, 0, 0);
        z = __builtin_amdgcn_mfma_f32_16x16x32_bf16(kf1, qf[j][1], z, 0, 0, 0);
        s[j][tt] = z;
      }
    }

    // P = exp2(S) straight (S already in log2 units); per-lane partial l
    s16x4 pa[2][2];
#pragma unroll
    for (int j = 0; j < 2; j++) {
      float rs = 0.f;
#pragma unroll
      for (int tt = 0; tt < 2; tt++) {
        bf16x4 pb;
#pragma unroll
        for (int r = 0; r < 4; r++) {
          float pe = __builtin_amdgcn_exp2f(s[j][tt][r]);
          rs += pe;
          pb[r] = (bf16)pe;
        }
        pa[j][tt] = __builtin_bit_cast(s16x4, pb);
      }
      lj[j] += rs;
    }

    // O^T += V^T P^T over this wave's key half.
    // V frag: row rv = ni*16+l16; global 8-key unit u = kh*4+2tt+(quad>>1)
    // -> key = kh*32+tt*16+quad*4+r ✓; slot = u^(rv&7) = u^(l16&7).
#pragma unroll
    for (int tt = 0; tt < 2; tt++) {
#pragma unroll
      for (int ni = 0; ni < 4; ni++) {
        int rv = ni * 16 + l16;
        int u = kh * 4 + 2 * tt + (quad >> 1);
        const bf16* vaddr =
            &lKV[p][4096 + rv * 64 + ((u ^ (l16 & 7)) * 8) + (quad & 1) * 4];
        s16x4 vb = __builtin_bit_cast(s16x4, *(const bf16x4*)vaddr);
#pragma unroll
        for (int j = 0; j < 2; j++)
          oaccT[j][ni] = __builtin_amdgcn_mfma_f32_16x16x16bf16_1k(
              vb, pa[j][tt], oaccT[j][ni], 0, 0, 0);
      }
    }
    p ^= 1;
  }

  // ---- cross key-half reduction (once per kernel) via LDS ----
  // SoA layout: vector slot c = j*4+ni at word (c*1024 + R*4), R = wq*64+lane.
  // Lanes stride 4 words -> 8-way b128 floor. 8 slots x 256 x 16B = 32KB = lKV.
  __syncthreads();  // K-loop LDS use done; lKV now scratch
  float* redO = (float*)&lKV[0][0];
  const int R = wq * 64 + lane;
  if (kh == 1) {
#pragma unroll
    for (int j = 0; j < 2; j++)
#pragma unroll
      for (int ni = 0; ni < 4; ni++)
        *(f32x4*)(redO + ((j * 4 + ni) * 1024 + R * 4)) = oaccT[j][ni];
    redL2[R * 2 + 0] = lj[0];
    redL2[R * 2 + 1] = lj[1];
  }
  __syncthreads();
  if (kh == 0) {
#pragma unroll
    for (int j = 0; j < 2; j++)
#pragma unroll
      for (int ni = 0; ni < 4; ni++)
        oaccT[j][ni] += *(const f32x4*)(redO + ((j * 4 + ni) * 1024 + R * 4));
    lj[0] += redL2[R * 2 + 0];
    lj[1] += redL2[R * 2 + 1];

    const int b = bh >> 4, h = bh & 15;
#pragma unroll
    for (int j = 0; j < 2; j++) {
      float l = lj[j];
      l += __shfl_xor(l, 16);
      l += __shfl_xor(l, 32);
      const float inv = 1.0f / l;
      bf16* dst = Ao + ((size_t)(b * NN) + qr0 + j * 16 + l16) * DD +
                  h * DKK + quad * 4;
#pragma unroll
      for (int ni = 0; ni < 4; ni++) {
        bf16x4 ov;
#pragma unroll
        for (int r = 0; r < 4; r++) ov[r] = (bf16)(oaccT[j][ni][r] * inv);
        *(bf16x4*)(dst + ni * 16) = ov;
      }
    }
  }
}

extern "C" void kernel_launch(void* const* d_in, const int* in_sizes, int n_in,
                              void* d_out, int out_size, void* d_ws,
                              size_t ws_size, hipStream_t stream) {
  const float* qin = (const float*)d_in[0];
  const float* kin = (const float*)d_in[1];
  const float* vin = (const float*)d_in[2];
  const float* Wq = (const float*)d_in[3];
  const float* bq = (const float*)d_in[4];
  const float* Wk = (const float*)d_in[5];
  const float* bk = (const float*)d_in[6];
  const float* Wv = (const float*)d_in[7];
  const float* bv = (const float*)d_in[8];
  const float* Wo = (const float*)d_in[9];
  const float* bo = (const float*)d_in[10];
  float* out = (float*)d_out;

  const int MN = BB * NN * DD;  // 4M elems
  const int WNel = DD * DD;     // 1M elems
  bf16* ws = (bf16*)d_ws;
  bf16* Xb = ws;                 // 12M elems (q,k,v bf16)
  bf16* Wb = Xb + 3 * MN;        // 4M elems (Wq,Wk,Wv,Wo bf16)
  bf16* Qp = Wb + 4 * WNel;      // 4M
  bf16* Kp = Qp + MN;            // 4M
  bf16* Vt = Kp + MN;            // 4M   -> 28M elems = 56MB
  bf16* Ao = Xb;                 // alias: Xb dead after k_qkv

  CvtArgs ca{{qin, kin, vin, Wq, Wk, Wv, Wo},
             {Xb, Xb + MN, Xb + 2 * MN, Wb, Wb + WNel, Wb + 2 * WNel,
              Wb + 3 * WNel},
             {MN, MN, MN, WNel, WNel, WNel, WNel}};
  k_cvt<<<dim3(2048, 7), 256, 0, stream>>>(ca);

  QkvArgs g{Xb, Wb, {bq, bk, bv}, {Qp, Kp, Vt}, SCALE * LOG2E};
  k_qkv<<<dim3(32, 8, 3), 256, 0, stream>>>(g);
  k_attn<<<dim3(32, 16), 512, 0, stream>>>(Qp, Kp, Vt, Ao);
  k_oproj<<<dim3(32, 16), 256, 0, stream>>>(Ao, Wb + 3 * WNel, bo, out);
}

// Round 8
// 201.605 us; speedup vs baseline: 2.2623x; 1.9455x over previous
//
#include <hip/hip_runtime.h>
#include <hip/hip_bf16.h>
#include <cstdint>
#include <cstddef>

#define BB 2
#define NN 2048
#define DD 1024
#define HH 16
#define DKK 64
#define SCALE 0.125f
#define LOG2E 1.4426950408889634f

typedef __bf16 bf16;
typedef __bf16 bf16x4 __attribute__((ext_vector_type(4)));
typedef __bf16 bf16x8 __attribute__((ext_vector_type(8)));
typedef float f32x4 __attribute__((ext_vector_type(4)));
typedef short s16x4 __attribute__((ext_vector_type(4)));

// async global->LDS, 16B/lane; LDS dst = wave-uniform base + lane*16.
#define GLD(gp, lp)                                                            \
  __builtin_amdgcn_global_load_lds(                                            \
      (const __attribute__((address_space(1))) void*)(gp),                     \
      (__attribute__((address_space(3))) void*)(lp), 16, 0, 0)

// ---------------- fp32 -> bf16 convert, all 7 tensors in one dispatch ------
struct CvtArgs { const float* s[7]; bf16* d[7]; int n[7]; };

__global__ void k_cvt(CvtArgs a) {
  const int seg = blockIdx.y;
  const float* __restrict__ s = a.s[seg];
  bf16* __restrict__ d = a.d[seg];
  int i = (blockIdx.x * 256 + threadIdx.x) * 8;
  if (i >= a.n[seg]) return;
  float4 f0 = *(const float4*)(s + i);
  float4 f1 = *(const float4*)(s + i + 4);
  bf16x8 o;
  o[0] = (bf16)f0.x; o[1] = (bf16)f0.y; o[2] = (bf16)f0.z; o[3] = (bf16)f0.w;
  o[4] = (bf16)f1.x; o[5] = (bf16)f1.y; o[6] = (bf16)f1.z; o[7] = (bf16)f1.w;
  *(bf16x8*)(d + i) = o;
}

// ---------------- GEMM body: out = oscale*(A @ W^T + bias) -----------------
// A:[M][1024] bf16, W:[1024][1024] bf16 (B^T layout). BK=64, GLD staging,
// 2-barrier m97 structure. Tile 128 x BN.
// LDS chunk swizzle: 8 chunks(16B)/row, slot c holds global chunk c^(r&7).
// mode 0: bf16 [b][h][row][dk]; mode 2: bf16 [b][h][dk][row]; mode 3: fp32.
template <int BN>
__device__ __forceinline__ void gemm_body(
    const bf16* __restrict__ A, const bf16* __restrict__ W,
    const float* __restrict__ bias, bf16* __restrict__ outB,
    float* __restrict__ outF, int mode, float oscale, int m0, int n0) {
  const int K = 1024;
  constexpr int NI = BN / 32;        // B-frags per wave
  constexpr int BI = BN * 8 / 256;   // B staging insts (chunks/256)
  __shared__ bf16 lA[128 * 64];
  __shared__ bf16 lB[BN * 64];
  const int t = threadIdx.x;
  const int lane = t & 63, quad = lane >> 4, l16 = lane & 15, w = t >> 6;
  const int wm = (w >> 1) * 64, wn = (w & 1) * (BN / 2);

  f32x4 acc[4][NI] = {};

  // staging map: chunk i = i4*256+t -> row i>>3, global chunk (i&7)^(row&7)
  const bf16* gA[4]; const bf16* gB[BI];
#pragma unroll
  for (int i4 = 0; i4 < 4; i4++) {
    int i = i4 * 256 + t;
    int r = i >> 3, c = (i & 7) ^ (r & 7);
    gA[i4] = A + (size_t)(m0 + r) * K + c * 8;
  }
#pragma unroll
  for (int i4 = 0; i4 < BI; i4++) {
    int i = i4 * 256 + t;
    int r = i >> 3, c = (i & 7) ^ (r & 7);
    gB[i4] = W + (size_t)(n0 + r) * K + c * 8;
  }

  for (int kb = 0; kb < K; kb += 64) {
    __syncthreads();  // prev step's LDS reads done
#pragma unroll
    for (int i4 = 0; i4 < 4; i4++) GLD(gA[i4] + kb, lA + (i4 * 256 + t) * 8);
#pragma unroll
    for (int i4 = 0; i4 < BI; i4++) GLD(gB[i4] + kb, lB + (i4 * 256 + t) * 8);
    __syncthreads();  // staging complete

#pragma unroll
    for (int kb2 = 0; kb2 < 2; kb2++) {
      bf16x8 af[4], bfr[NI];
      const int ch = ((kb2 * 4 + quad) ^ (l16 & 7)) * 8;
#pragma unroll
      for (int i = 0; i < 4; i++)
        af[i] = *(const bf16x8*)(lA + (wm + i * 16 + l16) * 64 + ch);
#pragma unroll
      for (int i = 0; i < NI; i++)
        bfr[i] = *(const bf16x8*)(lB + (wn + i * 16 + l16) * 64 + ch);
#pragma unroll
      for (int mi = 0; mi < 4; mi++)
#pragma unroll
        for (int ni = 0; ni < NI; ni++)
          acc[mi][ni] = __builtin_amdgcn_mfma_f32_16x16x32_bf16(
              af[mi], bfr[ni], acc[mi][ni], 0, 0, 0);
    }
  }

  // epilogue: C/D layout col=lane&15, row=quad*4+reg
  if (mode == 2) {
    // Vt [b][h][dk][row] output: per-wave 64x64 LDS transpose, then
    // coalesced bf16x8 stores along `row` (verified round 1: +14us on qkv).
    __syncthreads();  // all waves done with lA/lB K-loop reads
    // wave scratch: [col][row] bf16, 16B-unit swizzle u ^= (col&7)
    bf16* scr = (w < 2 ? lA : lB) + (w & 1) * 4096;
#pragma unroll
    for (int ni = 0; ni < NI; ni++) {
      int c = ni * 16 + l16;                 // local col (dk)
      float bs = bias[n0 + wn + c];
#pragma unroll
      for (int mi = 0; mi < 4; mi++) {
        int u = (mi * 2 + (quad >> 1)) ^ (c & 7);  // 16B unit (rows rr>>3)
        bf16x4 pv;
#pragma unroll
        for (int r = 0; r < 4; r++)
          pv[r] = (bf16)((acc[mi][ni][r] + bs) * oscale);
        // rr = mi*16 + quad*4 + r; elem-in-unit = (rr&7) = (quad&1)*4 + r
        *(bf16x4*)(scr + c * 64 + u * 8 + (quad & 1) * 4) = pv;
      }
    }
    __syncthreads();
    {
      const int gm0 = m0 + wm;
      const int b = gm0 >> 11, row0 = gm0 & 2047;
#pragma unroll
      for (int it = 0; it < 8; it++) {
        int c = it * 8 + (lane >> 3);
        int u = (lane & 7) ^ (lane >> 3);
        bf16x8 val = *(const bf16x8*)(scr + c * 64 + u * 8);
        int gn = n0 + wn + c;
        int h = gn >> 6, dk = gn & 63;
        *(bf16x8*)(outB + ((size_t)(b * HH + h) * DKK + dk) * NN + row0 +
                   (lane & 7) * 8) = val;
      }
    }
    return;
  }
#pragma unroll
  for (int mi = 0; mi < 4; mi++) {
#pragma unroll
    for (int ni = 0; ni < NI; ni++) {
#pragma unroll
      for (int r = 0; r < 4; r++) {
        int gm = m0 + wm + mi * 16 + quad * 4 + r;
        int gn = n0 + wn + ni * 16 + l16;
        float v = (acc[mi][ni][r] + bias[gn]) * oscale;
        if (mode == 3) {
          outF[(size_t)gm * 1024 + gn] = v;
        } else {
          int b = gm >> 11, row = gm & 2047;
          int h = gn >> 6, dk = gn & 63;
          outB[((size_t)(b * HH + h) * NN + row) * DKK + dk] = (bf16)v;
        }
      }
    }
  }
}

struct QkvArgs {
  const bf16* A; const bf16* W; const float* b[3]; bf16* o[3]; float sc0;
};

// grid (x=m-panel 32, y=n-panel 8, z=gemm): XCD = linear_id%8 = m-panel%8,
// so all 24 blocks (8 n-panels x 3 gemms) sharing an A panel sit on ONE XCD
// -> A (24MB, the big tensor) fetched ~once; W panels cycle through L2/L3.
__global__ __launch_bounds__(256, 3) void k_qkv(QkvArgs g) {
  const int z = blockIdx.z;
  gemm_body<128>(g.A + (size_t)z * 4194304, g.W + (size_t)z * 1048576,
                 g.b[z], g.o[z], nullptr, z == 2 ? 2 : 0,
                 z == 0 ? g.sc0 : 1.0f, blockIdx.x * 128, blockIdx.y * 128);
}

// grid (x=m-panel 32, y=n-panel 16): XCD = m-panel%8 -> Ao (8MB) shared per
// XCD; W (2MB) cycles. 512 blocks, 24KB LDS.
__global__ __launch_bounds__(256, 4) void k_oproj(
    const bf16* __restrict__ A, const bf16* __restrict__ W,
    const float* __restrict__ bias, float* __restrict__ out) {
  gemm_body<64>(A, W, bias, nullptr, out, 3, 1.0f, blockIdx.x * 128,
                blockIdx.y * 64);
}

// ---------------- flash attention (key-split waves, no-max softmax) --------
// Qp pre-scaled by SCALE*LOG2E. Qp,Kp:[B][H][N][DK]; Vt:[B][H][DK][N];
// Ao:[B][N][H*DK].
// 512 thr = 8 waves = 4 qrow-pairs (wq) x 2 key-halves (kh); QBLK=128,
// KVBLK=64. Per buffer: [0,4096) K tile 64keys x 64dk, [4096,8192) V tile
// 64dk x 64keys, both 8 chunks(16B)/row, slot c holds global chunk c^(row&7).
// LDS 34KB -> up to 4 blocks/CU at VGPR<=64.
// !! launch_bounds MUST be (512, 4): rounds 6-7 used (512, 8), which forced
// the allocator to 32 VGPRs -> full scratch spill -> ~1GB HBM traffic/dispatch
// (FETCH 408MB, WRITE 540MB) and 235-305us. Do not raise the min-waves arg.
// V IS LDS-staged (round-6 V-direct-global also contributed FETCH blowup).
// shfl row-sum (ones-MFMA regressed r2); no s_setprio (regressed r1);
// SoA kh-merge (r5: -1.4M bank conflicts).
__global__ __launch_bounds__(512, 4) void k_attn(
    const bf16* __restrict__ Qp, const bf16* __restrict__ Kp,
    const bf16* __restrict__ Vt, bf16* __restrict__ Ao) {
  __shared__ bf16 lKV[2][8192];  // 32KB: per buf K 8KB + V 8KB
  __shared__ float redL2[512];   // 2KB (kh=1 lj spill for merge)
  const int t = threadIdx.x;
  const int lane = t & 63, quad = lane >> 4, l16 = lane & 15, w = t >> 6;
  const int wq = w & 3;   // qrow pair
  const int kh = w >> 2;  // key half (32 keys)
  const int bh = blockIdx.x;  // XCD = bh%8 -> K/V L2-resident per XCD
  const int qt = blockIdx.y;
  const bf16* Qb = Qp + (size_t)bh * NN * DKK;
  const bf16* Kb = Kp + (size_t)bh * NN * DKK;
  const bf16* Vb = Vt + (size_t)bh * DKK * NN;

  // Q B-frags (n=qrow=l16, k=dk=quad*8+j); 2 strips of 16 rows
  const int qr0 = qt * 128 + wq * 32;
  bf16x8 qf[2][2];
#pragma unroll
  for (int j = 0; j < 2; j++)
#pragma unroll
    for (int kq = 0; kq < 2; kq++)
      qf[j][kq] = *(const bf16x8*)(Qb + (size_t)(qr0 + j * 16 + l16) * DKK +
                                   kq * 32 + quad * 8);

  float lj[2] = {0.f, 0.f};
  f32x4 oaccT[2][4] = {};  // O^T partials: rows dk=ni*16+quad*4+r, col=l16

  // staging: both K and V tiles are 64 rows x 8 chunks(16B); chunk i=t ->
  // row i>>3, slot i&7 holds global chunk (i&7)^(row&7). 512 thr x 16B = 8KB.
  const int rS = t >> 3, cS = (t & 7) ^ (rS & 7);
  const bf16* gK = Kb + (size_t)rS * DKK + cS * 8;  // K row = key
  const bf16* gV = Vb + (size_t)rS * NN + cS * 8;   // V row = dk, cols = keys
  const int swzK0 = (quad ^ (l16 & 7)) * 8;
  const int swzK1 = ((4 + quad) ^ (l16 & 7)) * 8;

  // prologue: stage tile 0 into buffer 0
  GLD(gK, &lKV[0][t * 8]);
  GLD(gV, &lKV[0][4096 + t * 8]);

  int p = 0;
  for (int kt = 0; kt < NN; kt += 64) {
    __syncthreads();  // tile-kt GLDs drained; all waves done with buf p^1
    if (kt + 64 < NN) {
      GLD(gK + (size_t)(kt + 64) * DKK, &lKV[p ^ 1][t * 8]);
      GLD(gV + (kt + 64), &lKV[p ^ 1][4096 + t * 8]);
    }

    // S^T = K Q^T over this wave's key half (keys kh*32 + tt*16 + quad*4+r)
    f32x4 s[2][2];
#pragma unroll
    for (int tt = 0; tt < 2; tt++) {
      const bf16* kbase = &lKV[p][((kh * 2 + tt) * 16 + l16) * 64];
      bf16x8 kf0 = *(const bf16x8*)(kbase + swzK0);
      bf16x8 kf1 = *(const bf16x8*)(kbase + swzK1);
#pragma unroll
      for (int j = 0; j < 2; j++) {
        f32x4 z = {0.f, 0.f, 0.f, 0.f};
        z = __builtin_amdgcn_mfma_f32_16x16x32_bf16(kf0, qf[j][0], z, 0, 0, 0);
        z = __builtin_amdgcn_mfma_f32_16x16x32_bf16(kf1, qf[j][1], z, 0, 0, 0);
        s[j][tt] = z;
      }
    }

    // P = exp2(S) straight (S already in log2 units); per-lane partial l
    s16x4 pa[2][2];
#pragma unroll
    for (int j = 0; j < 2; j++) {
      float rs = 0.f;
#pragma unroll
      for (int tt = 0; tt < 2; tt++) {
        bf16x4 pb;
#pragma unroll
        for (int r = 0; r < 4; r++) {
          float pe = __builtin_amdgcn_exp2f(s[j][tt][r]);
          rs += pe;
          pb[r] = (bf16)pe;
        }
        pa[j][tt] = __builtin_bit_cast(s16x4, pb);
      }
      lj[j] += rs;
    }

    // O^T += V^T P^T over this wave's key half.
    // V frag: row rv = ni*16+l16; global 8-key unit u = kh*4+2tt+(quad>>1)
    // -> key = kh*32+tt*16+quad*4+r ✓; slot = u^(rv&7) = u^(l16&7).
#pragma unroll
    for (int tt = 0; tt < 2; tt++) {
#pragma unroll
      for (int ni = 0; ni < 4; ni++) {
        int rv = ni * 16 + l16;
        int u = kh * 4 + 2 * tt + (quad >> 1);
        const bf16* vaddr =
            &lKV[p][4096 + rv * 64 + ((u ^ (l16 & 7)) * 8) + (quad & 1) * 4];
        s16x4 vb = __builtin_bit_cast(s16x4, *(const bf16x4*)vaddr);
#pragma unroll
        for (int j = 0; j < 2; j++)
          oaccT[j][ni] = __builtin_amdgcn_mfma_f32_16x16x16bf16_1k(
              vb, pa[j][tt], oaccT[j][ni], 0, 0, 0);
      }
    }
    p ^= 1;
  }

  // ---- cross key-half reduction (once per kernel) via LDS ----
  // SoA layout: vector slot c = j*4+ni at word (c*1024 + R*4), R = wq*64+lane.
  // Lanes stride 4 words -> 8-way b128 floor. 8 slots x 256 x 16B = 32KB = lKV.
  __syncthreads();  // K-loop LDS use done; lKV now scratch
  float* redO = (float*)&lKV[0][0];
  const int R = wq * 64 + lane;
  if (kh == 1) {
#pragma unroll
    for (int j = 0; j < 2; j++)
#pragma unroll
      for (int ni = 0; ni < 4; ni++)
        *(f32x4*)(redO + ((j * 4 + ni) * 1024 + R * 4)) = oaccT[j][ni];
    redL2[R * 2 + 0] = lj[0];
    redL2[R * 2 + 1] = lj[1];
  }
  __syncthreads();
  if (kh == 0) {
#pragma unroll
    for (int j = 0; j < 2; j++)
#pragma unroll
      for (int ni = 0; ni < 4; ni++)
        oaccT[j][ni] += *(const f32x4*)(redO + ((j * 4 + ni) * 1024 + R * 4));
    lj[0] += redL2[R * 2 + 0];
    lj[1] += redL2[R * 2 + 1];

    const int b = bh >> 4, h = bh & 15;
#pragma unroll
    for (int j = 0; j < 2; j++) {
      float l = lj[j];
      l += __shfl_xor(l, 16);
      l += __shfl_xor(l, 32);
      const float inv = 1.0f / l;
      bf16* dst = Ao + ((size_t)(b * NN) + qr0 + j * 16 + l16) * DD +
                  h * DKK + quad * 4;
#pragma unroll
      for (int ni = 0; ni < 4; ni++) {
        bf16x4 ov;
#pragma unroll
        for (int r = 0; r < 4; r++) ov[r] = (bf16)(oaccT[j][ni][r] * inv);
        *(bf16x4*)(dst + ni * 16) = ov;
      }
    }
  }
}

extern "C" void kernel_launch(void* const* d_in, const int* in_sizes, int n_in,
                              void* d_out, int out_size, void* d_ws,
                              size_t ws_size, hipStream_t stream) {
  const float* qin = (const float*)d_in[0];
  const float* kin = (const float*)d_in[1];
  const float* vin = (const float*)d_in[2];
  const float* Wq = (const float*)d_in[3];
  const float* bq = (const float*)d_in[4];
  const float* Wk = (const float*)d_in[5];
  const float* bk = (const float*)d_in[6];
  const float* Wv = (const float*)d_in[7];
  const float* bv = (const float*)d_in[8];
  const float* Wo = (const float*)d_in[9];
  const float* bo = (const float*)d_in[10];
  float* out = (float*)d_out;

  const int MN = BB * NN * DD;  // 4M elems
  const int WNel = DD * DD;     // 1M elems
  bf16* ws = (bf16*)d_ws;
  bf16* Xb = ws;                 // 12M elems (q,k,v bf16)
  bf16* Wb = Xb + 3 * MN;        // 4M elems (Wq,Wk,Wv,Wo bf16)
  bf16* Qp = Wb + 4 * WNel;      // 4M
  bf16* Kp = Qp + MN;            // 4M
  bf16* Vt = Kp + MN;            // 4M   -> 28M elems = 56MB
  bf16* Ao = Xb;                 // alias: Xb dead after k_qkv

  CvtArgs ca{{qin, kin, vin, Wq, Wk, Wv, Wo},
             {Xb, Xb + MN, Xb + 2 * MN, Wb, Wb + WNel, Wb + 2 * WNel,
              Wb + 3 * WNel},
             {MN, MN, MN, WNel, WNel, WNel, WNel}};
  k_cvt<<<dim3(2048, 7), 256, 0, stream>>>(ca);

  QkvArgs g{Xb, Wb, {bq, bk, bv}, {Qp, Kp, Vt}, SCALE * LOG2E};
  k_qkv<<<dim3(32, 8, 3), 256, 0, stream>>>(g);
  k_attn<<<dim3(32, 16), 512, 0, stream>>>(Qp, Kp, Vt, Ao);
  k_oproj<<<dim3(32, 16), 256, 0, stream>>>(Ao, Wb + 3 * WNel, bo, out);
}